// Round 4
// baseline (196.078 us; speedup 1.0000x reference)
//
#include <hip/hip_runtime.h>

// LinearBin: out = x @ sign(W)^T + bias   (B=131072, IN=OUT=512, fp32)
// bf16 MFMA GEMM. W pre-binarized to 16x16x32-fragment-major bf16 in d_ws.
// v3: latency-focused. 256-thread blocks (BM=64,BN=128), LDS cut to 16KB
//     (epilogue reuses A-tile LDS, fm-looped per-wave transpose),
//     launch_bounds(256,5) -> 5 blocks/CU target, B-frag register pipeline,
//     XCD swizzle keeps the 4 N-strips of an M-strip on one XCD.

#define BATCH   131072
#define IN_F    512
#define OUT_F   512
#define BM      64
#define BN      128
#define BK      64
#define NTILES  (IN_F / BK)   // 8

using f32x4  = __attribute__((ext_vector_type(4))) float;
using short8 = __attribute__((ext_vector_type(8))) short;
using usv4   = __attribute__((ext_vector_type(4))) unsigned short;
using usv8   = __attribute__((ext_vector_type(8))) unsigned short;

__device__ __forceinline__ unsigned short f2bf(float f) {
    union { float f; unsigned int u; } c{f};
    unsigned int u = c.u;
    return (unsigned short)((u + 0x7FFFu + ((u >> 16) & 1u)) >> 16); // RTNE
}

// ---------------- prep: binarize W into fragment-major bf16 (verified r1) ----
// wf[((kt*32 + nf)*64 + lane)*8 + j] = sign(W[nf*16 + (lane&15)][kt*32 + (lane>>4)*8 + j])
__global__ void prep_w(const float* __restrict__ W, unsigned short* __restrict__ wf) {
    int t = blockIdx.x * blockDim.x + threadIdx.x; // 32768 threads
    int lane = t & 63;
    int nf   = (t >> 6) & 31;
    int kt   = t >> 11;
    int n = nf * 16 + (lane & 15);
    int k = kt * 32 + ((lane >> 4) << 3);
    const float* src = W + n * IN_F + k;
    f32x4 w0 = *(const f32x4*)(src);
    f32x4 w1 = *(const f32x4*)(src + 4);
    usv8 o;
#pragma unroll
    for (int j = 0; j < 4; ++j) {
        o[j]     = (w0[j] >= 0.0f) ? 0x3F80u : 0xBF80u;
        o[j + 4] = (w1[j] >= 0.0f) ? 0x3F80u : 0xBF80u;
    }
    *(usv8*)(wf + (size_t)t * 8) = o;
}

// ---------------- GEMM ----------------
__global__ __launch_bounds__(256, 5) void gemm_bin(
    const float* __restrict__ X, const unsigned short* __restrict__ WF,
    const float* __restrict__ bias, float* __restrict__ out) {

    // 16KB total: double-buffered A tile during K-loop; reused by epilogue.
    __shared__ __align__(16) char smem[2 * BM * BK * 2];

    const int tid  = threadIdx.x;
    const int lane = tid & 63;
    const int wv   = tid >> 6;            // 0..3 -> 32-col strip

    // XCD swizzle: i&7 -> XCD; within an XCD's stream, nh varies fastest so the
    // 4 N-strips of one M-strip are dispatch-adjacent (x L2 reuse).
    const int i   = blockIdx.x;           // grid = 8192
    const int xcd = i & 7;
    const int j   = i >> 3;
    const int nh  = j & 3;
    const int mg  = j >> 2;               // 0..255
    const int m0  = (mg * 8 + xcd) * BM;
    const int col0 = nh * BN + wv * 32;

    // staging: 4 threads cover one row; each thread 4x16B granules (stride 64B)
    const int srow = tid >> 2;            // 0..63
    const int sg   = tid & 3;
    const float* xs = X + (size_t)(m0 + srow) * IN_F + sg * 4;
    const int swz_w = (srow & 7) << 4;
    int wb[4];
#pragma unroll
    for (int p = 0; p < 4; ++p) wb[p] = (srow * 128 + sg * 8 + p * 32) ^ swz_w;

    // A-frag read geometry
    const int ar = lane & 15;
    const int ak = (lane >> 4) << 4;
    const int swz_r = (ar & 7) << 4;
    const int nf0 = nh * 8 + wv * 2;

    f32x4 acc[4][2];
#pragma unroll
    for (int fm = 0; fm < 4; ++fm)
#pragma unroll
        for (int fn = 0; fn < 2; ++fn)
            acc[fm][fn] = (f32x4){0.f, 0.f, 0.f, 0.f};

#define LOADB(dst, g)                                                          \
    {                                                                          \
        _Pragma("unroll")                                                      \
        for (int fn = 0; fn < 2; ++fn)                                         \
            dst[fn] = *(const short8*)(WF +                                    \
                ((size_t)(((g) * 32 + nf0 + fn) * 64 + lane)) * 8);            \
    }

    short8 bf[2][2];
    // prologue: stage tile 0, load B-frags for kt=0,1
    {
        f32x4 cur[4];
#pragma unroll
        for (int p = 0; p < 4; ++p) cur[p] = *(const f32x4*)(xs + p * 16);
#pragma unroll
        for (int p = 0; p < 4; ++p) {
            usv4 pk;
#pragma unroll
            for (int q = 0; q < 4; ++q) pk[q] = f2bf(cur[p][q]);
            *(usv4*)(smem + wb[p]) = pk;
        }
    }
    LOADB(bf[0], 0);
    LOADB(bf[1], 1);
    __syncthreads();

    f32x4 na[4];
#pragma unroll
    for (int t = 0; t < NTILES; ++t) {
        const int buf = t & 1;
        if (t < NTILES - 1) {
#pragma unroll
            for (int p = 0; p < 4; ++p)
                na[p] = *(const f32x4*)(xs + (t + 1) * BK + p * 16);
        }
        const char* ab = smem + buf * (BM * BK * 2);
        short8 afr[4];
        // ---- h = 0
#pragma unroll
        for (int fm = 0; fm < 4; ++fm)
            afr[fm] = *(const short8*)(ab + ((((fm * 16 + ar) * 128) + ak) ^ swz_r));
#pragma unroll
        for (int fm = 0; fm < 4; ++fm)
#pragma unroll
            for (int fn = 0; fn < 2; ++fn)
                acc[fm][fn] = __builtin_amdgcn_mfma_f32_16x16x32_bf16(
                    afr[fm], bf[0][fn], acc[fm][fn], 0, 0, 0);
        if (t < NTILES - 1) LOADB(bf[0], 2 * t + 2);
        // ---- h = 1
#pragma unroll
        for (int fm = 0; fm < 4; ++fm)
            afr[fm] = *(const short8*)(ab + ((((fm * 16 + ar) * 128) + 64 + ak) ^ swz_r));
#pragma unroll
        for (int fm = 0; fm < 4; ++fm)
#pragma unroll
            for (int fn = 0; fn < 2; ++fn)
                acc[fm][fn] = __builtin_amdgcn_mfma_f32_16x16x32_bf16(
                    afr[fm], bf[1][fn], acc[fm][fn], 0, 0, 0);
        if (t < NTILES - 1) LOADB(bf[1], 2 * t + 3);
        // stage tile t+1 into the other buffer
        if (t < NTILES - 1) {
            char* wbase = smem + (buf ^ 1) * (BM * BK * 2);
#pragma unroll
            for (int p = 0; p < 4; ++p) {
                usv4 pk;
#pragma unroll
                for (int q = 0; q < 4; ++q) pk[q] = f2bf(na[p][q]);
                *(usv4*)(wbase + wb[p]) = pk;
            }
        }
        __syncthreads();
    }

    // ---------- epilogue: per-wave 2KB transpose chunks, reusing smem ----------
    const int lcol  = lane & 15;
    const int lrow4 = (lane >> 4) << 2;
    float bv[2];
#pragma unroll
    for (int fn = 0; fn < 2; ++fn) bv[fn] = bias[col0 + fn * 16 + lcol];

    char* lw = smem + wv * 2048;
#pragma unroll
    for (int fm = 0; fm < 4; ++fm) {
#pragma unroll
        for (int fn = 0; fn < 2; ++fn)
#pragma unroll
            for (int jj = 0; jj < 4; ++jj) {
                const int r16  = lrow4 + jj;
                const int byte = (r16 * 128 + (fn * 16 + lcol) * 4) ^ ((r16 & 7) << 4);
                *(float*)(lw + byte) = acc[fm][fn][jj] + bv[fn];
            }
        asm volatile("s_waitcnt lgkmcnt(0)" ::: "memory");
#pragma unroll
        for (int it = 0; it < 2; ++it) {
            const int rr   = it * 8 + (lane >> 3);
            const int byte = (rr * 128 + (lane & 7) * 16) ^ ((rr & 7) << 4);
            f32x4 v = *(const f32x4*)(lw + byte);
            *(f32x4*)(out + (size_t)(m0 + fm * 16 + rr) * OUT_F + col0 + (lane & 7) * 4) = v;
        }
        asm volatile("s_waitcnt lgkmcnt(0)" ::: "memory");
    }
#undef LOADB
}

extern "C" void kernel_launch(void* const* d_in, const int* in_sizes, int n_in,
                              void* d_out, int out_size, void* d_ws, size_t ws_size,
                              hipStream_t stream) {
    const float* X    = (const float*)d_in[0];
    const float* W    = (const float*)d_in[1];
    const float* bias = (const float*)d_in[2];
    float* o          = (float*)d_out;
    unsigned short* wf = (unsigned short*)d_ws; // 512KB fragment-major binarized W

    hipLaunchKernelGGL(prep_w, dim3(128), dim3(256), 0, stream, W, wf);
    hipLaunchKernelGGL(gemm_bin, dim3((BATCH / BM) * (OUT_F / BN)), dim3(256), 0, stream,
                       X, wf, bias, o);
}

// Round 5
// 179.144 us; speedup vs baseline: 1.0945x; 1.0945x over previous
//
#include <hip/hip_runtime.h>
#include <stdint.h>

// LinearBin: out = x @ sign(W)^T + bias   (B=131072, IN=OUT=512, fp32)
// v5: T3+T4 counted-vmcnt pipeline. x staged fp32 via global_load_lds DMA
//     (pre-swizzled source, linear dest), raw s_barrier + s_waitcnt vmcnt(8)
//     so 2 tile-loads + B-frags stay in flight across barriers. fp32->bf16
//     conversion at fragment-read time via v_cvt_pk_bf16_f32. No ds_writes
//     in main loop; one barrier per K-tile. BK=32, NBUF=4 (32KB LDS).

#define BATCH   131072
#define IN_F    512
#define OUT_F   512
#define BM      64
#define BN      128
#define BK      32              // floats per K-tile (one mfma k-step)
#define NT      (IN_F / BK)     // 16
#define NBUF    4
#define TILE_B  (BM * BK * 4)   // 8192 bytes per buffer

using f32x4  = __attribute__((ext_vector_type(4))) float;
using short8 = __attribute__((ext_vector_type(8))) short;
using usv8   = __attribute__((ext_vector_type(8))) unsigned short;
using u32    = uint32_t;

// ---------------- prep: binarize W into fragment-major bf16 (verified r1) ----
// wf[((kt*32 + nf)*64 + lane)*8 + j] = sign(W[nf*16 + (lane&15)][kt*32 + (lane>>4)*8 + j])
__global__ void prep_w(const float* __restrict__ W, unsigned short* __restrict__ wf) {
    int t = blockIdx.x * blockDim.x + threadIdx.x; // 32768 threads
    int lane = t & 63;
    int nf   = (t >> 6) & 31;
    int kt   = t >> 11;
    int n = nf * 16 + (lane & 15);
    int k = kt * 32 + ((lane >> 4) << 3);
    const float* src = W + n * IN_F + k;
    f32x4 w0 = *(const f32x4*)(src);
    f32x4 w1 = *(const f32x4*)(src + 4);
    usv8 o;
#pragma unroll
    for (int j = 0; j < 4; ++j) {
        o[j]     = (w0[j] >= 0.0f) ? 0x3F80u : 0xBF80u;
        o[j + 4] = (w1[j] >= 0.0f) ? 0x3F80u : 0xBF80u;
    }
    *(usv8*)(wf + (size_t)t * 8) = o;
}

// ---------------- GEMM ----------------
__global__ __launch_bounds__(256, 4) void gemm_bin(
    const float* __restrict__ X, const unsigned short* __restrict__ WF,
    const float* __restrict__ bias, float* __restrict__ out) {

    // NBUF ring of fp32 x-tiles, [64 rows][128B], XOR-swizzled content.
    __shared__ __align__(16) char smem[NBUF * TILE_B]; // 32KB

    const int tid  = threadIdx.x;
    const int lane = tid & 63;
    const int wv   = tid >> 6;            // 0..3 -> 32-col strip

    // XCD swizzle: i&7 -> XCD; nh varies fastest within an XCD's stream.
    const int i   = blockIdx.x;           // grid = 8192
    const int xcd = i & 7;
    const int j   = i >> 3;
    const int nh  = j & 3;
    const int mg  = j >> 2;
    const int m0  = (mg * 8 + xcd) * BM;
    const int col0 = nh * BN + wv * 32;

    // ---- DMA staging geometry (2 x 16B granules per thread per tile) ----
    // linear LDS offset o = tid*16 (+4096): row = o>>7, slot = (o>>4)&7.
    // content at (row, slot) = x[m0+row][k0 + 4*(slot ^ (row&7))]  (pre-swizzled src)
    const int drow0 = tid >> 3;           // 0..31
    const int dslot = tid & 7;
    const float* g0 = X + (size_t)(m0 + drow0) * IN_F + 4 * (dslot ^ (drow0 & 7));
    const float* g1 = X + (size_t)(m0 + drow0 + 32) * IN_F + 4 * (dslot ^ ((drow0 + 32) & 7));
    char* ldsw0 = smem + wv * 1024;       // wave-uniform base; HW adds lane*16
    char* ldsw1 = smem + wv * 1024 + 4096;

#define ISSUE_STAGE(t_)                                                        \
    {                                                                          \
        const int b_ = (t_) & (NBUF - 1);                                      \
        __builtin_amdgcn_global_load_lds(                                      \
            (const __attribute__((address_space(1))) void*)(g0 + (t_) * BK),   \
            (__attribute__((address_space(3))) void*)(ldsw0 + b_ * TILE_B),    \
            16, 0, 0);                                                         \
        __builtin_amdgcn_global_load_lds(                                      \
            (const __attribute__((address_space(1))) void*)(g1 + (t_) * BK),   \
            (__attribute__((address_space(3))) void*)(ldsw1 + b_ * TILE_B),    \
            16, 0, 0);                                                         \
    }

    // ---- B-frag geometry ----
    const int nf0 = nh * 8 + wv * 2;
#define LOADB(dst, kt_)                                                        \
    {                                                                          \
        _Pragma("unroll")                                                      \
        for (int fn = 0; fn < 2; ++fn)                                         \
            dst[fn] = *(const short8*)(WF +                                    \
                ((size_t)(((kt_) * 32 + nf0 + fn) * 64 + lane)) * 8);          \
    }

    // ---- A-frag read geometry: lane l: row=(l&15)+16fm, floats (l>>4)*8..+8
    const int ar = lane & 15;
    const int aq = lane >> 4;

    f32x4 acc[4][2];
#pragma unroll
    for (int fm = 0; fm < 4; ++fm)
#pragma unroll
        for (int fn = 0; fn < 2; ++fn)
            acc[fm][fn] = (f32x4){0.f, 0.f, 0.f, 0.f};

    short8 bf[2][2];
    // prologue: DMA tiles 0,1; B-frags kt=0
    ISSUE_STAGE(0);
    ISSUE_STAGE(1);
    LOADB(bf[0], 0);

#pragma unroll
    for (int t = 0; t < NT; ++t) {
        if (t + 1 < NT) LOADB(bf[(t + 1) & 1], t + 1);
        if (t + 2 < NT) ISSUE_STAGE(t + 2);
        // counted wait: tile t's 2 DMA loads are (outstanding-8)-oldest
        asm volatile("s_waitcnt vmcnt(8)" ::: "memory");
        __builtin_amdgcn_sched_barrier(0);
        __builtin_amdgcn_s_barrier();
        __builtin_amdgcn_sched_barrier(0);

        const char* ab = smem + (t & (NBUF - 1)) * TILE_B;
        short8 afr[4];
#pragma unroll
        for (int fm = 0; fm < 4; ++fm) {
            const int row = fm * 16 + ar;
            const int b0  = row * 128 + ((2 * aq) ^ (row & 7)) * 16;
            f32x4 lo = *(const f32x4*)(ab + b0);
            f32x4 hi = *(const f32x4*)(ab + (b0 ^ 16));
            u32 w0, w1, w2, w3;
            asm("v_cvt_pk_bf16_f32 %0, %1, %2" : "=v"(w0) : "v"(lo[0]), "v"(lo[1]));
            asm("v_cvt_pk_bf16_f32 %0, %1, %2" : "=v"(w1) : "v"(lo[2]), "v"(lo[3]));
            asm("v_cvt_pk_bf16_f32 %0, %1, %2" : "=v"(w2) : "v"(hi[0]), "v"(hi[1]));
            asm("v_cvt_pk_bf16_f32 %0, %1, %2" : "=v"(w3) : "v"(hi[2]), "v"(hi[3]));
            union { u32 w[4]; short8 v; } pk;
            pk.w[0] = w0; pk.w[1] = w1; pk.w[2] = w2; pk.w[3] = w3;
            afr[fm] = pk.v;
        }
#pragma unroll
        for (int fm = 0; fm < 4; ++fm)
#pragma unroll
            for (int fn = 0; fn < 2; ++fn)
                acc[fm][fn] = __builtin_amdgcn_mfma_f32_16x16x32_bf16(
                    afr[fm], bf[t & 1][fn], acc[fm][fn], 0, 0, 0);
    }
#undef ISSUE_STAGE
#undef LOADB

    // ---------- epilogue: per-wave 2KB LDS transpose chunks (conflict-free) ----
    const int lcol  = lane & 15;
    const int lrow4 = (lane >> 4) << 2;
    float bv[2];
#pragma unroll
    for (int fn = 0; fn < 2; ++fn) bv[fn] = bias[col0 + fn * 16 + lcol];

    char* lw = smem + wv * 2048;   // waves use disjoint chunks; no cross-wave sync
#pragma unroll
    for (int fm = 0; fm < 4; ++fm) {
#pragma unroll
        for (int fn = 0; fn < 2; ++fn)
#pragma unroll
            for (int jj = 0; jj < 4; ++jj) {
                const int r16  = lrow4 + jj;
                const int byte = (r16 * 128 + (fn * 16 + lcol) * 4) ^ ((r16 & 7) << 4);
                *(float*)(lw + byte) = acc[fm][fn][jj] + bv[fn];
            }
        asm volatile("s_waitcnt lgkmcnt(0)" ::: "memory");
#pragma unroll
        for (int it = 0; it < 2; ++it) {
            const int rr   = it * 8 + (lane >> 3);
            const int byte = (rr * 128 + (lane & 7) * 16) ^ ((rr & 7) << 4);
            f32x4 v = *(const f32x4*)(lw + byte);
            *(f32x4*)(out + (size_t)(m0 + fm * 16 + rr) * OUT_F + col0 + (lane & 7) * 4) = v;
        }
        asm volatile("s_waitcnt lgkmcnt(0)" ::: "memory");
    }
}

extern "C" void kernel_launch(void* const* d_in, const int* in_sizes, int n_in,
                              void* d_out, int out_size, void* d_ws, size_t ws_size,
                              hipStream_t stream) {
    const float* X    = (const float*)d_in[0];
    const float* W    = (const float*)d_in[1];
    const float* bias = (const float*)d_in[2];
    float* o          = (float*)d_out;
    unsigned short* wf = (unsigned short*)d_ws; // 512KB fragment-major binarized W

    hipLaunchKernelGGL(prep_w, dim3(128), dim3(256), 0, stream, W, wf);
    hipLaunchKernelGGL(gemm_bin, dim3((BATCH / BM) * (OUT_F / BN)), dim3(256), 0, stream,
                       X, wf, bias, o);
}